// Round 13
// baseline (107.529 us; speedup 1.0000x reference)
//
#include <hip/hip_runtime.h>

#define NTOK 4096
#define DMODEL 512
#define DEMB 64
#define DCAT 576
#define NHEAD 8
#define DHEAD 64
#define QSCALE 0.18033688011112042f  // (1/8) * log2(e)

typedef float f32x4 __attribute__((ext_vector_type(4)));
typedef float f32x16 __attribute__((ext_vector_type(16)));
typedef short s16x8 __attribute__((ext_vector_type(8)));
typedef unsigned short u16;
typedef u16 u16x4 __attribute__((ext_vector_type(4)));
typedef u16 u16x8 __attribute__((ext_vector_type(8)));
typedef unsigned int u32;

__device__ __forceinline__ u16 f2bf(float f) {
  union { float f; unsigned u; } v; v.f = f;
  unsigned r = v.u + 0x7fffu + ((v.u >> 16) & 1u);
  return (u16)(r >> 16);
}

__device__ __forceinline__ float bf2f(u16 u) {
  union { unsigned u; float f; } v; v.u = ((unsigned)u) << 16;
  return v.f;
}

__device__ __forceinline__ u32 cvtpk_bf16(float lo, float hi) {
  u32 r;
  asm("v_cvt_pk_bf16_f32 %0, %1, %2" : "=v"(r) : "v"(lo), "v"(hi));
  return r;
}

__device__ __forceinline__ void gload16(const void* g, void* lds) {
  __builtin_amdgcn_global_load_lds((const __attribute__((address_space(1))) u32*)g,
                                   (__attribute__((address_space(3))) u32*)lds, 16, 0, 0);
}

// prep: fused wtrans (blocks 0..359) + lnx (360..1383) + lne (1384..2407)
__global__ void prep_kernel(const float* __restrict__ x, const float* __restrict__ emb,
                            const float* __restrict__ Wq, const float* __restrict__ Wk,
                            const float* __restrict__ Wv, const float* __restrict__ Wf1,
                            const float* __restrict__ Wf2,
                            const float* __restrict__ g1, const float* __restrict__ b1,
                            const float* __restrict__ g2, const float* __restrict__ b2,
                            float* __restrict__ xt, u16* __restrict__ qkin,
                            u16* __restrict__ Tqkv, u16* __restrict__ Tf1,
                            u16* __restrict__ Tf2) {
  __shared__ float tile[64][65];
  int b = blockIdx.x;
  int tid = threadIdx.x;
  if (b < 360) {
    int w = b / 72, r = b % 72;
    int kbi = r % 9, nbi = r / 9;
    const float* src; u16* dst; int Ksrc, Kdst;
    if (w == 0)      { src = Wq;  dst = Tqkv;              Ksrc = 576; Kdst = 576; }
    else if (w == 1) { src = Wk;  dst = Tqkv + 512 * 576;  Ksrc = 576; Kdst = 576; }
    else if (w == 2) { src = Wv;  dst = Tqkv + 1024 * 576; Ksrc = 512; Kdst = 576; }
    else if (w == 3) { src = Wf1; dst = Tf1;               Ksrc = 512; Kdst = 512; }
    else             { src = Wf2; dst = Tf2;               Ksrc = 512; Kdst = 512; }
    int kb = kbi * 64;
    if (kb >= Kdst) return;
    int nb = nbi * 64;
    #pragma unroll
    for (int i = 0; i < 16; ++i) {
      int idx = tid + i * 256;
      int rr = idx >> 6, c = idx & 63;
      tile[rr][c] = (kb + rr < Ksrc) ? src[(size_t)(kb + rr) * DMODEL + nb + c] : 0.0f;
    }
    __syncthreads();
    #pragma unroll
    for (int i = 0; i < 16; ++i) {
      int idx = tid + i * 256;
      int rr = idx >> 6, c = idx & 63;
      dst[(size_t)(nb + rr) * Kdst + kb + c] = f2bf(tile[c][rr]);
    }
  } else if (b < 1384) {
    int row = (b - 360) * 4 + (tid >> 6);
    int lane = tid & 63;
    const float* xr = x + (size_t)row * DMODEL + lane * 8;
    float v[8];
    float4 a0 = *(const float4*)xr;
    float4 a1 = *(const float4*)(xr + 4);
    v[0]=a0.x; v[1]=a0.y; v[2]=a0.z; v[3]=a0.w; v[4]=a1.x; v[5]=a1.y; v[6]=a1.z; v[7]=a1.w;
    float s = 0.f, ss = 0.f;
    #pragma unroll
    for (int j = 0; j < 8; ++j) { s += v[j]; ss += v[j]*v[j]; }
    #pragma unroll
    for (int off = 32; off > 0; off >>= 1) { s += __shfl_xor(s, off); ss += __shfl_xor(ss, off); }
    float mu = s * (1.0f / DMODEL);
    float var = ss * (1.0f / DMODEL) - mu * mu;
    float rs = rsqrtf(var + 1e-5f);
    float4 g0 = *(const float4*)(g1 + lane * 8);
    float4 g1v = *(const float4*)(g1 + lane * 8 + 4);
    float4 b0 = *(const float4*)(b1 + lane * 8);
    float4 b1v = *(const float4*)(b1 + lane * 8 + 4);
    float gg[8] = {g0.x,g0.y,g0.z,g0.w,g1v.x,g1v.y,g1v.z,g1v.w};
    float bb[8] = {b0.x,b0.y,b0.z,b0.w,b1v.x,b1v.y,b1v.z,b1v.w};
    float o[8]; u16x8 ob;
    #pragma unroll
    for (int j = 0; j < 8; ++j) { o[j] = (v[j]-mu)*rs*gg[j] + bb[j]; ob[j] = f2bf(o[j]); }
    float* xo = xt + (size_t)row * DMODEL + lane * 8;
    *(float4*)xo = make_float4(o[0],o[1],o[2],o[3]);
    *(float4*)(xo + 4) = make_float4(o[4],o[5],o[6],o[7]);
    *(u16x8*)(qkin + (size_t)row * DCAT + lane * 8) = ob;
  } else {
    int row = (b - 1384) * 4 + (tid >> 6);
    int lane = tid & 63;
    float v = emb[(size_t)row * DEMB + lane];
    float s = v, ss = v * v;
    #pragma unroll
    for (int off = 32; off > 0; off >>= 1) { s += __shfl_xor(s, off); ss += __shfl_xor(ss, off); }
    float mu = s * (1.0f / DEMB);
    float var = ss * (1.0f / DEMB) - mu * mu;
    float rs = rsqrtf(var + 1e-5f);
    float o = (v - mu) * rs * g2[lane] + b2[lane];
    qkin[(size_t)row * DCAT + DMODEL + lane] = f2bf(o);
  }
}

// ln3: merges 8 attention partial slices (obuf bf16 + lbuf), updates xt in
// place (xt += O/l) and writes hb = LN(xt_new) as bf16.
__global__ void ln3_kernel(float* __restrict__ xt, const float* __restrict__ g,
                           const float* __restrict__ b, u16* __restrict__ hb,
                           const u16* __restrict__ obuf, const float* __restrict__ lbuf) {
  int row = blockIdx.x * 4 + (threadIdx.x >> 6);
  int lane = threadIdx.x & 63;
  int h = lane >> 3;
  int dh0 = (lane & 7) * 8;
  float* xr = xt + (size_t)row * DMODEL + lane * 8;
  float v[8];
  float4 a0 = *(const float4*)xr;
  float4 a1 = *(const float4*)(xr + 4);
  v[0]=a0.x; v[1]=a0.y; v[2]=a0.z; v[3]=a0.w; v[4]=a1.x; v[5]=a1.y; v[6]=a1.z; v[7]=a1.w;
  float osum[8] = {};
  float lsum = 0.f;
  #pragma unroll
  for (int s = 0; s < 8; ++s) {
    size_t hb_idx = (size_t)(s * 8 + h) * NTOK + row;
    u16x8 ov = *(const u16x8*)(obuf + hb_idx * 64 + dh0);
    lsum += lbuf[hb_idx];
    #pragma unroll
    for (int j = 0; j < 8; ++j) osum[j] += bf2f(ov[j]);
  }
  float rcpl = 1.0f / lsum;
  #pragma unroll
  for (int j = 0; j < 8; ++j) v[j] += osum[j] * rcpl;
  *(float4*)xr = make_float4(v[0],v[1],v[2],v[3]);
  *(float4*)(xr + 4) = make_float4(v[4],v[5],v[6],v[7]);
  float s = 0.f, ss = 0.f;
  #pragma unroll
  for (int j = 0; j < 8; ++j) { s += v[j]; ss += v[j]*v[j]; }
  #pragma unroll
  for (int off = 32; off > 0; off >>= 1) { s += __shfl_xor(s, off); ss += __shfl_xor(ss, off); }
  float mu = s * (1.0f / DMODEL);
  float var = ss * (1.0f / DMODEL) - mu * mu;
  float rs = rsqrtf(var + 1e-5f);
  float4 g0 = *(const float4*)(g + lane * 8);
  float4 g1v = *(const float4*)(g + lane * 8 + 4);
  float4 b0 = *(const float4*)(b + lane * 8);
  float4 b1v = *(const float4*)(b + lane * 8 + 4);
  float gg[8] = {g0.x,g0.y,g0.z,g0.w,g1v.x,g1v.y,g1v.z,g1v.w};
  float bb[8] = {b0.x,b0.y,b0.z,b0.w,b1v.x,b1v.y,b1v.z,b1v.w};
  u16x8 ob;
  #pragma unroll
  for (int j = 0; j < 8; ++j) ob[j] = f2bf((v[j]-mu)*rs*gg[j] + bb[j]);
  *(u16x8*)(hb + (size_t)row * DMODEL + lane * 8) = ob;
}

// QKV GEMM: BM=128, BN=64, BK=64, 4 waves (2x2, each 64x32 output).
// V token columns stored with bits 2<->3 swapped per 16-token group.
__global__ __launch_bounds__(256) void gemm_qkv_kernel(
    const u16* __restrict__ A, const u16* __restrict__ Bt, u16* __restrict__ outb) {
  __shared__ __align__(16) u16 smem[12288];
  u16* Al = smem;
  u16* Bl = smem + 8192;
  int tid = threadIdx.x, lane = tid & 63, wid = tid >> 6;
  int li = lane & 15, g4 = lane >> 4;
  int n0 = blockIdx.x * 64, m0 = blockIdx.y * 128;
  int wr = (wid >> 1) * 64, wc = (wid & 1) * 32;
  f32x4 acc[4][2] = {};
  for (int k0 = 0; k0 < DCAT; k0 += 64) {
    #pragma unroll
    for (int i = 0; i < 4; ++i) {
      int idx = i * 256 + tid;
      int row = idx >> 3, cb = (idx & 7) * 8;
      gload16(A + (size_t)(m0 + row) * DCAT + k0 + cb, (char*)Al + idx * 16);
    }
    #pragma unroll
    for (int i = 0; i < 2; ++i) {
      int idx = i * 256 + tid;
      int row = idx >> 3, cb = (idx & 7) * 8;
      gload16(Bt + (size_t)(n0 + row) * DCAT + k0 + cb, (char*)Bl + idx * 16);
    }
    __syncthreads();
    #pragma unroll
    for (int kk = 0; kk < 2; ++kk) {
      s16x8 af[4], bfv[2];
      #pragma unroll
      for (int mi = 0; mi < 4; ++mi)
        af[mi] = *(const s16x8*)&Al[(wr + mi * 16 + li) * 64 + kk * 32 + g4 * 8];
      #pragma unroll
      for (int ni = 0; ni < 2; ++ni)
        bfv[ni] = *(const s16x8*)&Bl[(wc + ni * 16 + li) * 64 + kk * 32 + g4 * 8];
      #pragma unroll
      for (int mi = 0; mi < 4; ++mi)
        #pragma unroll
        for (int ni = 0; ni < 2; ++ni)
          acc[mi][ni] = __builtin_amdgcn_mfma_f32_16x16x32_bf16(af[mi], bfv[ni], acc[mi][ni], 0, 0, 0);
    }
    __syncthreads();
  }
  if (n0 < 1024) {
    float scale = (n0 < 512) ? QSCALE : 1.0f;
    int nb = (n0 < 512) ? n0 : n0 - 512;
    u16* dst = outb + ((n0 < 512) ? 0 : (size_t)NTOK * DMODEL);
    #pragma unroll
    for (int mi = 0; mi < 4; ++mi)
      #pragma unroll
      for (int ni = 0; ni < 2; ++ni) {
        int col = nb + wc + ni * 16 + li;
        int h = col >> 6, dh = col & 63;
        #pragma unroll
        for (int r = 0; r < 4; ++r) {
          int row = m0 + wr + mi * 16 + g4 * 4 + r;
          dst[((size_t)h * NTOK + row) * DHEAD + dh] = f2bf(acc[mi][ni][r] * scale);
        }
      }
  } else {
    u16* vT = outb + (size_t)2 * NTOK * DMODEL;
    u16* tp = smem;  // [64 dh][136 tokens padded]
    __syncthreads();
    #pragma unroll
    for (int mi = 0; mi < 4; ++mi)
      #pragma unroll
      for (int ni = 0; ni < 2; ++ni) {
        int cl = wc + ni * 16 + li;
        int r0 = wr + mi * 16 + g4 * 4;
        int r0p = (r0 & ~12) | ((r0 & 4) << 1) | ((r0 & 8) >> 1);  // swap token bits 2,3
        u16x4 pk;
        pk[0] = f2bf(acc[mi][ni][0]); pk[1] = f2bf(acc[mi][ni][1]);
        pk[2] = f2bf(acc[mi][ni][2]); pk[3] = f2bf(acc[mi][ni][3]);
        *(u16x4*)&tp[cl * 136 + r0p] = pk;
      }
    __syncthreads();
    for (int c = tid; c < 1024; c += 256) {
      int cl = c >> 4, seg = c & 15;
      u16x8 v = *(const u16x8*)&tp[cl * 136 + seg * 8];
      *(u16x8*)&vT[(size_t)(n0 - 1024 + cl) * NTOK + m0 + seg * 8] = v;
    }
  }
}

// FFN GEMM: BM=128, BN=64, BK=64, 4 waves (2x2, each 64x32). MODE 3: bias+relu
// bf16. MODE 4: bias + xt residual -> f32 out. grid (8, 32) = 256 blocks.
template<int MODE>
__global__ __launch_bounds__(256) void gemm_kernel(
    const u16* __restrict__ A, int lda, const u16* __restrict__ Bt, int K,
    u16* __restrict__ outb, float* __restrict__ outf,
    const float* __restrict__ bias, const float* __restrict__ xt) {
  __shared__ __align__(16) u16 smem[12288];
  u16* Al = smem;
  u16* Bl = smem + 8192;
  int tid = threadIdx.x, lane = tid & 63, wid = tid >> 6;
  int li = lane & 15, g4 = lane >> 4;
  int n0 = blockIdx.x * 64, m0 = blockIdx.y * 128;
  int wr = (wid >> 1) * 64, wc = (wid & 1) * 32;
  f32x4 acc[4][2] = {};
  for (int k0 = 0; k0 < K; k0 += 64) {
    #pragma unroll
    for (int i = 0; i < 4; ++i) {
      int idx = i * 256 + tid;
      int row = idx >> 3, cb = (idx & 7) * 8;
      gload16(A + (size_t)(m0 + row) * lda + k0 + cb, (char*)Al + idx * 16);
    }
    #pragma unroll
    for (int i = 0; i < 2; ++i) {
      int idx = i * 256 + tid;
      int row = idx >> 3, cb = (idx & 7) * 8;
      gload16(Bt + (size_t)(n0 + row) * K + k0 + cb, (char*)Bl + idx * 16);
    }
    __syncthreads();
    #pragma unroll
    for (int kk = 0; kk < 2; ++kk) {
      s16x8 af[4], bfv[2];
      #pragma unroll
      for (int mi = 0; mi < 4; ++mi)
        af[mi] = *(const s16x8*)&Al[(wr + mi * 16 + li) * 64 + kk * 32 + g4 * 8];
      #pragma unroll
      for (int ni = 0; ni < 2; ++ni)
        bfv[ni] = *(const s16x8*)&Bl[(wc + ni * 16 + li) * 64 + kk * 32 + g4 * 8];
      #pragma unroll
      for (int mi = 0; mi < 4; ++mi)
        #pragma unroll
        for (int ni = 0; ni < 2; ++ni)
          acc[mi][ni] = __builtin_amdgcn_mfma_f32_16x16x32_bf16(af[mi], bfv[ni], acc[mi][ni], 0, 0, 0);
    }
    __syncthreads();
  }
  #pragma unroll
  for (int mi = 0; mi < 4; ++mi)
    #pragma unroll
    for (int ni = 0; ni < 2; ++ni) {
      int col = n0 + wc + ni * 16 + li;
      float bv = bias[col];
      #pragma unroll
      for (int r = 0; r < 4; ++r) {
        int row = m0 + wr + mi * 16 + g4 * 4 + r;
        float v = acc[mi][ni][r] + bv;
        if (MODE == 3) {
          v = fmaxf(v, 0.0f);
          outb[(size_t)row * DMODEL + col] = f2bf(v);
        } else {
          outf[(size_t)row * DMODEL + col] = v + xt[(size_t)row * DMODEL + col];
        }
      }
    }
}

// fused flash attention v12: verified v10 core (32x32x16 MFMA, in-register
// softmax via pre-permuted V, conflict-free chunk-transposed K/V LDS), now
// 8 key-splits of 512 keys: grid 1024 = 8h x 8ks x 16qt -> 4 blocks/CU =
// 32 waves/CU (FULL occupancy; v10 had 16). Same total staging traffic.
// 8 waves x 32 q = 256 q rows/block, 8 tiles of 64 keys. LDS 32 KB. VGPR 64.
__global__ __launch_bounds__(512, 1) void attn_kernel(
    const u16* __restrict__ qh, const u16* __restrict__ kh,
    const u16* __restrict__ vT, u16* __restrict__ obuf, float* __restrict__ lbuf) {
  __shared__ __align__(16) u16 kbufT[2][4096];  // chunk s = dhchunk*64 + key
  __shared__ __align__(16) u16 vbufT[2][4096];  // chunk s = keychunk*64 + dh (keys permuted)
  int tid = threadIdx.x, lane = tid & 63, w = tid >> 6;
  int lq = lane & 31, h5 = lane >> 5;
  int h = blockIdx.x & 7, ks = (blockIdx.x >> 3) & 7, qt = blockIdx.x >> 6;
  int q0w = qt * 256 + w * 32;
  int ko0 = ks * 512;
  const u16* qb = qh + ((size_t)h * NTOK + q0w + lq) * DHEAD;
  s16x8 qf[4];
  #pragma unroll
  for (int kc = 0; kc < 4; ++kc)
    qf[kc] = *(const s16x8*)(qb + kc * 16 + h5 * 8);
  f32x16 o[2] = {};
  float lsum = 0.f;
  const char* kh_b = (const char*)(kh + (size_t)h * NTOK * DHEAD);
  const char* v_b = (const char*)(vT + (size_t)h * DHEAD * NTOK);

  // 512 threads stage 512 K-chunks + 512 V-chunks: 1 of each per thread
  auto stage = [&](int c, int ko) {
    int lo6 = tid & 63, r6 = tid >> 6;
    gload16(kh_b + (size_t)(ko + lo6) * 128 + r6 * 16, (char*)&kbufT[c][0] + tid * 16);
    gload16(v_b + (size_t)lo6 * (NTOK * 2) + (size_t)(ko + r6 * 8) * 2,
            (char*)&vbufT[c][0] + tid * 16);
  };

  stage(0, ko0);
  asm volatile("s_waitcnt vmcnt(0)" ::: "memory");
  __builtin_amdgcn_sched_barrier(0);
  __syncthreads();

  for (int t = 0; t < 8; ++t) {
    int cur = t & 1;
    if (t < 7) stage(cur ^ 1, ko0 + (t + 1) * 64);
    const u16* Kl = &kbufT[cur][0];
    const u16* Vl = &vbufT[cur][0];
    #pragma unroll
    for (int kb2 = 0; kb2 < 2; ++kb2) {
      f32x16 st = {};
      #pragma unroll
      for (int kc = 0; kc < 4; ++kc) {
        s16x8 kf = *(const s16x8*)(Kl + ((kc * 2 + h5) * 64 + kb2 * 32 + lq) * 8);
        st = __builtin_amdgcn_mfma_f32_32x32x16_bf16(kf, qf[kc], st, 0, 0, 0);
      }
      float p[16];
      #pragma unroll
      for (int r = 0; r < 16; ++r) { p[r] = __builtin_amdgcn_exp2f(st[r]); lsum += p[r]; }
      #pragma unroll
      for (int cl = 0; cl < 2; ++cl) {
        int b = cl * 8;
        union { u32 wv[4]; s16x8 hv; } pu;
        pu.wv[0] = cvtpk_bf16(p[b + 0], p[b + 1]);
        pu.wv[1] = cvtpk_bf16(p[b + 2], p[b + 3]);
        pu.wv[2] = cvtpk_bf16(p[b + 4], p[b + 5]);
        pu.wv[3] = cvtpk_bf16(p[b + 6], p[b + 7]);
        int kcg = kb2 * 2 + cl;
        #pragma unroll
        for (int dhalf = 0; dhalf < 2; ++dhalf) {
          s16x8 bv = *(const s16x8*)(Vl + ((kcg * 2 + h5) * 64 + dhalf * 32 + lq) * 8);
          o[dhalf] = __builtin_amdgcn_mfma_f32_32x32x16_bf16(pu.hv, bv, o[dhalf], 0, 0, 0);
        }
      }
    }
    if (t < 7) {
      asm volatile("s_waitcnt vmcnt(0)" ::: "memory");
      __builtin_amdgcn_sched_barrier(0);
      __syncthreads();
    }
  }

  lsum += __shfl_xor(lsum, 32);
  size_t slice = (size_t)(ks * 8 + h) * NTOK;
  if (h5 == 0) lbuf[slice + q0w + lq] = lsum;
  u16* ob = obuf + (slice + q0w) * 64;
  #pragma unroll
  for (int dhalf = 0; dhalf < 2; ++dhalf)
    #pragma unroll
    for (int r = 0; r < 16; ++r) {
      int crow = (r & 3) + 8 * (r >> 2) + 4 * h5;
      ob[(size_t)crow * 64 + dhalf * 32 + lq] = f2bf(o[dhalf][r]);
    }
}

extern "C" void kernel_launch(void* const* d_in, const int* in_sizes, int n_in,
                              void* d_out, int out_size, void* d_ws, size_t ws_size,
                              hipStream_t stream) {
  const float* x   = (const float*)d_in[0];
  const float* emb = (const float*)d_in[1];
  const float* Wq  = (const float*)d_in[2];
  const float* Wk  = (const float*)d_in[3];
  const float* Wv  = (const float*)d_in[4];
  const float* g1  = (const float*)d_in[5];
  const float* b1  = (const float*)d_in[6];
  const float* g2  = (const float*)d_in[7];
  const float* b2  = (const float*)d_in[8];
  const float* g3  = (const float*)d_in[9];
  const float* b3  = (const float*)d_in[10];
  const float* Wf1 = (const float*)d_in[11];
  const float* bf1 = (const float*)d_in[12];
  const float* Wf2 = (const float*)d_in[13];
  const float* bf2 = (const float*)d_in[14];
  float* out = (float*)d_out;

  char* ws = (char*)d_ws;
  size_t off = 0;
  auto alloc = [&](size_t bytes) { void* p = ws + off; off += (bytes + 255) & ~255ull; return p; };
  float* xt = (float*)alloc((size_t)NTOK * DMODEL * 4);
  u16* qkin = (u16*)alloc((size_t)NTOK * DCAT * 2);
  u16* hb   = (u16*)alloc((size_t)NTOK * DMODEL * 2);
  u16* r1   = (u16*)alloc((size_t)NTOK * DMODEL * 2);
  u16* qkvh = (u16*)alloc((size_t)3 * NTOK * DMODEL * 2);  // qhd | khd | vT contiguous
  u16* Tqkv = (u16*)alloc((size_t)1536 * DCAT * 2);
  u16* Tf1  = (u16*)alloc((size_t)DMODEL * DMODEL * 2);
  u16* Tf2  = (u16*)alloc((size_t)DMODEL * DMODEL * 2);
  u16* obuf = (u16*)alloc((size_t)8 * NHEAD * NTOK * DHEAD * 2);  // 32 MB
  float* lbuf = (float*)alloc((size_t)8 * NHEAD * NTOK * 4);      // 1 MB
  u16* qhd = qkvh;
  u16* khd = qkvh + (size_t)NTOK * DMODEL;
  u16* vTd = qkvh + (size_t)2 * NTOK * DMODEL;

  prep_kernel<<<2408, 256, 0, stream>>>(x, emb, Wq, Wk, Wv, Wf1, Wf2,
                                        g1, b1, g2, b2, xt, qkin, Tqkv, Tf1, Tf2);
  gemm_qkv_kernel<<<dim3(24, 32), 256, 0, stream>>>(qkin, Tqkv, qkvh);
  attn_kernel<<<1024, 512, 0, stream>>>(qhd, khd, vTd, obuf, lbuf);
  ln3_kernel<<<1024, 256, 0, stream>>>(xt, g3, b3, hb, obuf, lbuf);
  gemm_kernel<3><<<dim3(8, 32), 256, 0, stream>>>(hb, DMODEL, Tf1, DMODEL, r1, nullptr, bf1, nullptr);
  gemm_kernel<4><<<dim3(8, 32), 256, 0, stream>>>(r1, DMODEL, Tf2, DMODEL, nullptr, out, bf2, xt);
}

// Round 14
// 95.080 us; speedup vs baseline: 1.1309x; 1.1309x over previous
//
#include <hip/hip_runtime.h>

#define NTOK 4096
#define DMODEL 512
#define DEMB 64
#define DCAT 576
#define NHEAD 8
#define DHEAD 64
#define QSCALE 0.18033688011112042f  // (1/8) * log2(e)

typedef float f32x4 __attribute__((ext_vector_type(4)));
typedef float f32x16 __attribute__((ext_vector_type(16)));
typedef short s16x8 __attribute__((ext_vector_type(8)));
typedef unsigned short u16;
typedef u16 u16x4 __attribute__((ext_vector_type(4)));
typedef u16 u16x8 __attribute__((ext_vector_type(8)));
typedef unsigned int u32;

__device__ __forceinline__ u16 f2bf(float f) {
  union { float f; unsigned u; } v; v.f = f;
  unsigned r = v.u + 0x7fffu + ((v.u >> 16) & 1u);
  return (u16)(r >> 16);
}

__device__ __forceinline__ float bf2f(u16 u) {
  union { unsigned u; float f; } v; v.u = ((unsigned)u) << 16;
  return v.f;
}

__device__ __forceinline__ u32 cvtpk_bf16(float lo, float hi) {
  u32 r;
  asm("v_cvt_pk_bf16_f32 %0, %1, %2" : "=v"(r) : "v"(lo), "v"(hi));
  return r;
}

__device__ __forceinline__ void gload16(const void* g, void* lds) {
  __builtin_amdgcn_global_load_lds((const __attribute__((address_space(1))) u32*)g,
                                   (__attribute__((address_space(3))) u32*)lds, 16, 0, 0);
}

// prep: fused wtrans (blocks 0..359) + lnx (360..1383) + lne (1384..2407)
__global__ void prep_kernel(const float* __restrict__ x, const float* __restrict__ emb,
                            const float* __restrict__ Wq, const float* __restrict__ Wk,
                            const float* __restrict__ Wv, const float* __restrict__ Wf1,
                            const float* __restrict__ Wf2,
                            const float* __restrict__ g1, const float* __restrict__ b1,
                            const float* __restrict__ g2, const float* __restrict__ b2,
                            float* __restrict__ xt, u16* __restrict__ qkin,
                            u16* __restrict__ Tqkv, u16* __restrict__ Tf1,
                            u16* __restrict__ Tf2) {
  __shared__ float tile[64][65];
  int b = blockIdx.x;
  int tid = threadIdx.x;
  if (b < 360) {
    int w = b / 72, r = b % 72;
    int kbi = r % 9, nbi = r / 9;
    const float* src; u16* dst; int Ksrc, Kdst;
    if (w == 0)      { src = Wq;  dst = Tqkv;              Ksrc = 576; Kdst = 576; }
    else if (w == 1) { src = Wk;  dst = Tqkv + 512 * 576;  Ksrc = 576; Kdst = 576; }
    else if (w == 2) { src = Wv;  dst = Tqkv + 1024 * 576; Ksrc = 512; Kdst = 576; }
    else if (w == 3) { src = Wf1; dst = Tf1;               Ksrc = 512; Kdst = 512; }
    else             { src = Wf2; dst = Tf2;               Ksrc = 512; Kdst = 512; }
    int kb = kbi * 64;
    if (kb >= Kdst) return;
    int nb = nbi * 64;
    #pragma unroll
    for (int i = 0; i < 16; ++i) {
      int idx = tid + i * 256;
      int rr = idx >> 6, c = idx & 63;
      tile[rr][c] = (kb + rr < Ksrc) ? src[(size_t)(kb + rr) * DMODEL + nb + c] : 0.0f;
    }
    __syncthreads();
    #pragma unroll
    for (int i = 0; i < 16; ++i) {
      int idx = tid + i * 256;
      int rr = idx >> 6, c = idx & 63;
      dst[(size_t)(nb + rr) * Kdst + kb + c] = f2bf(tile[c][rr]);
    }
  } else if (b < 1384) {
    int row = (b - 360) * 4 + (tid >> 6);
    int lane = tid & 63;
    const float* xr = x + (size_t)row * DMODEL + lane * 8;
    float v[8];
    float4 a0 = *(const float4*)xr;
    float4 a1 = *(const float4*)(xr + 4);
    v[0]=a0.x; v[1]=a0.y; v[2]=a0.z; v[3]=a0.w; v[4]=a1.x; v[5]=a1.y; v[6]=a1.z; v[7]=a1.w;
    float s = 0.f, ss = 0.f;
    #pragma unroll
    for (int j = 0; j < 8; ++j) { s += v[j]; ss += v[j]*v[j]; }
    #pragma unroll
    for (int off = 32; off > 0; off >>= 1) { s += __shfl_xor(s, off); ss += __shfl_xor(ss, off); }
    float mu = s * (1.0f / DMODEL);
    float var = ss * (1.0f / DMODEL) - mu * mu;
    float rs = rsqrtf(var + 1e-5f);
    float4 g0 = *(const float4*)(g1 + lane * 8);
    float4 g1v = *(const float4*)(g1 + lane * 8 + 4);
    float4 b0 = *(const float4*)(b1 + lane * 8);
    float4 b1v = *(const float4*)(b1 + lane * 8 + 4);
    float gg[8] = {g0.x,g0.y,g0.z,g0.w,g1v.x,g1v.y,g1v.z,g1v.w};
    float bb[8] = {b0.x,b0.y,b0.z,b0.w,b1v.x,b1v.y,b1v.z,b1v.w};
    float o[8]; u16x8 ob;
    #pragma unroll
    for (int j = 0; j < 8; ++j) { o[j] = (v[j]-mu)*rs*gg[j] + bb[j]; ob[j] = f2bf(o[j]); }
    float* xo = xt + (size_t)row * DMODEL + lane * 8;
    *(float4*)xo = make_float4(o[0],o[1],o[2],o[3]);
    *(float4*)(xo + 4) = make_float4(o[4],o[5],o[6],o[7]);
    *(u16x8*)(qkin + (size_t)row * DCAT + lane * 8) = ob;
  } else {
    int row = (b - 1384) * 4 + (tid >> 6);
    int lane = tid & 63;
    float v = emb[(size_t)row * DEMB + lane];
    float s = v, ss = v * v;
    #pragma unroll
    for (int off = 32; off > 0; off >>= 1) { s += __shfl_xor(s, off); ss += __shfl_xor(ss, off); }
    float mu = s * (1.0f / DEMB);
    float var = ss * (1.0f / DEMB) - mu * mu;
    float rs = rsqrtf(var + 1e-5f);
    float o = (v - mu) * rs * g2[lane] + b2[lane];
    qkin[(size_t)row * DCAT + DMODEL + lane] = f2bf(o);
  }
}

// ln3: merges attention partials (obuf bf16 slices + lbuf), updates xt in
// place (xt += O/l) and writes hb = LN(xt_new) as bf16.
__global__ void ln3_kernel(float* __restrict__ xt, const float* __restrict__ g,
                           const float* __restrict__ b, u16* __restrict__ hb,
                           const u16* __restrict__ obuf, const float* __restrict__ lbuf) {
  int row = blockIdx.x * 4 + (threadIdx.x >> 6);
  int lane = threadIdx.x & 63;
  int h = lane >> 3;
  int dh0 = (lane & 7) * 8;
  float* xr = xt + (size_t)row * DMODEL + lane * 8;
  float v[8];
  float4 a0 = *(const float4*)xr;
  float4 a1 = *(const float4*)(xr + 4);
  v[0]=a0.x; v[1]=a0.y; v[2]=a0.z; v[3]=a0.w; v[4]=a1.x; v[5]=a1.y; v[6]=a1.z; v[7]=a1.w;
  float osum[8] = {};
  float lsum = 0.f;
  #pragma unroll
  for (int s = 0; s < 4; ++s) {
    size_t hb_idx = (size_t)(s * 8 + h) * NTOK + row;
    u16x8 ov = *(const u16x8*)(obuf + hb_idx * 64 + dh0);
    lsum += lbuf[hb_idx];
    #pragma unroll
    for (int j = 0; j < 8; ++j) osum[j] += bf2f(ov[j]);
  }
  float rcpl = 1.0f / lsum;
  #pragma unroll
  for (int j = 0; j < 8; ++j) v[j] += osum[j] * rcpl;
  *(float4*)xr = make_float4(v[0],v[1],v[2],v[3]);
  *(float4*)(xr + 4) = make_float4(v[4],v[5],v[6],v[7]);
  float s = 0.f, ss = 0.f;
  #pragma unroll
  for (int j = 0; j < 8; ++j) { s += v[j]; ss += v[j]*v[j]; }
  #pragma unroll
  for (int off = 32; off > 0; off >>= 1) { s += __shfl_xor(s, off); ss += __shfl_xor(ss, off); }
  float mu = s * (1.0f / DMODEL);
  float var = ss * (1.0f / DMODEL) - mu * mu;
  float rs = rsqrtf(var + 1e-5f);
  float4 g0 = *(const float4*)(g + lane * 8);
  float4 g1v = *(const float4*)(g + lane * 8 + 4);
  float4 b0 = *(const float4*)(b + lane * 8);
  float4 b1v = *(const float4*)(b + lane * 8 + 4);
  float gg[8] = {g0.x,g0.y,g0.z,g0.w,g1v.x,g1v.y,g1v.z,g1v.w};
  float bb[8] = {b0.x,b0.y,b0.z,b0.w,b1v.x,b1v.y,b1v.z,b1v.w};
  u16x8 ob;
  #pragma unroll
  for (int j = 0; j < 8; ++j) ob[j] = f2bf((v[j]-mu)*rs*gg[j] + bb[j]);
  *(u16x8*)(hb + (size_t)row * DMODEL + lane * 8) = ob;
}

// QKV GEMM: BM=128, BN=64, BK=64, 4 waves (2x2, each 64x32 output).
// V token columns stored with bits 2<->3 swapped per 16-token group.
__global__ __launch_bounds__(256) void gemm_qkv_kernel(
    const u16* __restrict__ A, const u16* __restrict__ Bt, u16* __restrict__ outb) {
  __shared__ __align__(16) u16 smem[12288];
  u16* Al = smem;
  u16* Bl = smem + 8192;
  int tid = threadIdx.x, lane = tid & 63, wid = tid >> 6;
  int li = lane & 15, g4 = lane >> 4;
  int n0 = blockIdx.x * 64, m0 = blockIdx.y * 128;
  int wr = (wid >> 1) * 64, wc = (wid & 1) * 32;
  f32x4 acc[4][2] = {};
  for (int k0 = 0; k0 < DCAT; k0 += 64) {
    #pragma unroll
    for (int i = 0; i < 4; ++i) {
      int idx = i * 256 + tid;
      int row = idx >> 3, cb = (idx & 7) * 8;
      gload16(A + (size_t)(m0 + row) * DCAT + k0 + cb, (char*)Al + idx * 16);
    }
    #pragma unroll
    for (int i = 0; i < 2; ++i) {
      int idx = i * 256 + tid;
      int row = idx >> 3, cb = (idx & 7) * 8;
      gload16(Bt + (size_t)(n0 + row) * DCAT + k0 + cb, (char*)Bl + idx * 16);
    }
    __syncthreads();
    #pragma unroll
    for (int kk = 0; kk < 2; ++kk) {
      s16x8 af[4], bfv[2];
      #pragma unroll
      for (int mi = 0; mi < 4; ++mi)
        af[mi] = *(const s16x8*)&Al[(wr + mi * 16 + li) * 64 + kk * 32 + g4 * 8];
      #pragma unroll
      for (int ni = 0; ni < 2; ++ni)
        bfv[ni] = *(const s16x8*)&Bl[(wc + ni * 16 + li) * 64 + kk * 32 + g4 * 8];
      #pragma unroll
      for (int mi = 0; mi < 4; ++mi)
        #pragma unroll
        for (int ni = 0; ni < 2; ++ni)
          acc[mi][ni] = __builtin_amdgcn_mfma_f32_16x16x32_bf16(af[mi], bfv[ni], acc[mi][ni], 0, 0, 0);
    }
    __syncthreads();
  }
  if (n0 < 1024) {
    float scale = (n0 < 512) ? QSCALE : 1.0f;
    int nb = (n0 < 512) ? n0 : n0 - 512;
    u16* dst = outb + ((n0 < 512) ? 0 : (size_t)NTOK * DMODEL);
    #pragma unroll
    for (int mi = 0; mi < 4; ++mi)
      #pragma unroll
      for (int ni = 0; ni < 2; ++ni) {
        int col = nb + wc + ni * 16 + li;
        int h = col >> 6, dh = col & 63;
        #pragma unroll
        for (int r = 0; r < 4; ++r) {
          int row = m0 + wr + mi * 16 + g4 * 4 + r;
          dst[((size_t)h * NTOK + row) * DHEAD + dh] = f2bf(acc[mi][ni][r] * scale);
        }
      }
  } else {
    u16* vT = outb + (size_t)2 * NTOK * DMODEL;
    u16* tp = smem;  // [64 dh][136 tokens padded]
    __syncthreads();
    #pragma unroll
    for (int mi = 0; mi < 4; ++mi)
      #pragma unroll
      for (int ni = 0; ni < 2; ++ni) {
        int cl = wc + ni * 16 + li;
        int r0 = wr + mi * 16 + g4 * 4;
        int r0p = (r0 & ~12) | ((r0 & 4) << 1) | ((r0 & 8) >> 1);  // swap token bits 2,3
        u16x4 pk;
        pk[0] = f2bf(acc[mi][ni][0]); pk[1] = f2bf(acc[mi][ni][1]);
        pk[2] = f2bf(acc[mi][ni][2]); pk[3] = f2bf(acc[mi][ni][3]);
        *(u16x4*)&tp[cl * 136 + r0p] = pk;
      }
    __syncthreads();
    for (int c = tid; c < 1024; c += 256) {
      int cl = c >> 4, seg = c & 15;
      u16x8 v = *(const u16x8*)&tp[cl * 136 + seg * 8];
      *(u16x8*)&vT[(size_t)(n0 - 1024 + cl) * NTOK + m0 + seg * 8] = v;
    }
  }
}

// FFN GEMM: BM=64, BN=64, BK=64, 4 waves. MODE 3: bias+relu bf16. MODE 4: bias
// + xt residual -> f32 out.
template<int MODE>
__global__ __launch_bounds__(256) void gemm_kernel(
    const u16* __restrict__ A, int lda, const u16* __restrict__ Bt, int K,
    u16* __restrict__ outb, float* __restrict__ outf,
    const float* __restrict__ bias, const float* __restrict__ xt) {
  __shared__ __align__(16) u16 smem[8192];
  u16* Al = smem;
  u16* Bl = smem + 4096;
  int tid = threadIdx.x, lane = tid & 63, wid = tid >> 6;
  int li = lane & 15, g4 = lane >> 4;
  int n0 = blockIdx.x * 64, m0 = blockIdx.y * 64;
  int wr = (wid >> 1) * 32, wc = (wid & 1) * 32;
  f32x4 acc[2][2] = {};
  for (int k0 = 0; k0 < K; k0 += 64) {
    #pragma unroll
    for (int i = 0; i < 2; ++i) {
      int idx = i * 256 + tid;
      int row = idx >> 3, cb = (idx & 7) * 8;
      gload16(A + (size_t)(m0 + row) * lda + k0 + cb, (char*)Al + idx * 16);
    }
    #pragma unroll
    for (int i = 0; i < 2; ++i) {
      int idx = i * 256 + tid;
      int row = idx >> 3, cb = (idx & 7) * 8;
      gload16(Bt + (size_t)(n0 + row) * K + k0 + cb, (char*)Bl + idx * 16);
    }
    __syncthreads();
    #pragma unroll
    for (int kk = 0; kk < 2; ++kk) {
      s16x8 af[2], bfv[2];
      #pragma unroll
      for (int mi = 0; mi < 2; ++mi)
        af[mi] = *(const s16x8*)&Al[(wr + mi * 16 + li) * 64 + kk * 32 + g4 * 8];
      #pragma unroll
      for (int ni = 0; ni < 2; ++ni)
        bfv[ni] = *(const s16x8*)&Bl[(wc + ni * 16 + li) * 64 + kk * 32 + g4 * 8];
      #pragma unroll
      for (int mi = 0; mi < 2; ++mi)
        #pragma unroll
        for (int ni = 0; ni < 2; ++ni)
          acc[mi][ni] = __builtin_amdgcn_mfma_f32_16x16x32_bf16(af[mi], bfv[ni], acc[mi][ni], 0, 0, 0);
    }
    __syncthreads();
  }
  #pragma unroll
  for (int mi = 0; mi < 2; ++mi)
    #pragma unroll
    for (int ni = 0; ni < 2; ++ni) {
      int col = n0 + wc + ni * 16 + li;
      float bv = bias[col];
      #pragma unroll
      for (int r = 0; r < 4; ++r) {
        int row = m0 + wr + mi * 16 + g4 * 4 + r;
        float v = acc[mi][ni][r] + bv;
        if (MODE == 3) {
          v = fmaxf(v, 0.0f);
          outb[(size_t)row * DMODEL + col] = f2bf(v);
        } else {
          outf[(size_t)row * DMODEL + col] = v + xt[(size_t)row * DMODEL + col];
        }
      }
    }
}

// fused flash attention (v10, measured 43.6us): 32x32x16 MFMA, in-register
// softmax via pre-permuted V, conflict-free chunk-transposed K/V LDS.
// 8 waves x 32 q = 256 q rows/block; grid 512 = 8h x 4ks x 16qt -> 2 blocks/CU,
// 16 waves/CU, zero tail. LDS 32 KB. VGPR 64.
__global__ __launch_bounds__(512, 1) void attn_kernel(
    const u16* __restrict__ qh, const u16* __restrict__ kh,
    const u16* __restrict__ vT, u16* __restrict__ obuf, float* __restrict__ lbuf) {
  __shared__ __align__(16) u16 kbufT[2][4096];  // chunk s = dhchunk*64 + key
  __shared__ __align__(16) u16 vbufT[2][4096];  // chunk s = keychunk*64 + dh (keys permuted)
  int tid = threadIdx.x, lane = tid & 63, w = tid >> 6;
  int lq = lane & 31, h5 = lane >> 5;
  int h = blockIdx.x & 7, ks = (blockIdx.x >> 3) & 3, qt = blockIdx.x >> 5;
  int q0w = qt * 256 + w * 32;
  int ko0 = ks * 1024;
  const u16* qb = qh + ((size_t)h * NTOK + q0w + lq) * DHEAD;
  s16x8 qf[4];
  #pragma unroll
  for (int kc = 0; kc < 4; ++kc)
    qf[kc] = *(const s16x8*)(qb + kc * 16 + h5 * 8);
  f32x16 o[2] = {};
  float lsum = 0.f;
  const char* kh_b = (const char*)(kh + (size_t)h * NTOK * DHEAD);
  const char* v_b = (const char*)(vT + (size_t)h * DHEAD * NTOK);

  // 512 threads stage 512 K-chunks + 512 V-chunks: 1 of each per thread
  auto stage = [&](int c, int ko) {
    int lo6 = tid & 63, r6 = tid >> 6;
    gload16(kh_b + (size_t)(ko + lo6) * 128 + r6 * 16, (char*)&kbufT[c][0] + tid * 16);
    gload16(v_b + (size_t)lo6 * (NTOK * 2) + (size_t)(ko + r6 * 8) * 2,
            (char*)&vbufT[c][0] + tid * 16);
  };

  stage(0, ko0);
  asm volatile("s_waitcnt vmcnt(0)" ::: "memory");
  __builtin_amdgcn_sched_barrier(0);
  __syncthreads();

  for (int t = 0; t < 16; ++t) {
    int cur = t & 1;
    if (t < 15) stage(cur ^ 1, ko0 + (t + 1) * 64);
    const u16* Kl = &kbufT[cur][0];
    const u16* Vl = &vbufT[cur][0];
    #pragma unroll
    for (int kb2 = 0; kb2 < 2; ++kb2) {
      f32x16 st = {};
      #pragma unroll
      for (int kc = 0; kc < 4; ++kc) {
        s16x8 kf = *(const s16x8*)(Kl + ((kc * 2 + h5) * 64 + kb2 * 32 + lq) * 8);
        st = __builtin_amdgcn_mfma_f32_32x32x16_bf16(kf, qf[kc], st, 0, 0, 0);
      }
      float p[16];
      #pragma unroll
      for (int r = 0; r < 16; ++r) { p[r] = __builtin_amdgcn_exp2f(st[r]); lsum += p[r]; }
      #pragma unroll
      for (int cl = 0; cl < 2; ++cl) {
        int b = cl * 8;
        union { u32 wv[4]; s16x8 hv; } pu;
        pu.wv[0] = cvtpk_bf16(p[b + 0], p[b + 1]);
        pu.wv[1] = cvtpk_bf16(p[b + 2], p[b + 3]);
        pu.wv[2] = cvtpk_bf16(p[b + 4], p[b + 5]);
        pu.wv[3] = cvtpk_bf16(p[b + 6], p[b + 7]);
        int kcg = kb2 * 2 + cl;
        #pragma unroll
        for (int dhalf = 0; dhalf < 2; ++dhalf) {
          s16x8 bv = *(const s16x8*)(Vl + ((kcg * 2 + h5) * 64 + dhalf * 32 + lq) * 8);
          o[dhalf] = __builtin_amdgcn_mfma_f32_32x32x16_bf16(pu.hv, bv, o[dhalf], 0, 0, 0);
        }
      }
    }
    if (t < 15) {
      asm volatile("s_waitcnt vmcnt(0)" ::: "memory");
      __builtin_amdgcn_sched_barrier(0);
      __syncthreads();
    }
  }

  lsum += __shfl_xor(lsum, 32);
  size_t slice = (size_t)(ks * 8 + h) * NTOK;
  if (h5 == 0) lbuf[slice + q0w + lq] = lsum;
  u16* ob = obuf + (slice + q0w) * 64;
  #pragma unroll
  for (int dhalf = 0; dhalf < 2; ++dhalf)
    #pragma unroll
    for (int r = 0; r < 16; ++r) {
      int crow = (r & 3) + 8 * (r >> 2) + 4 * h5;
      ob[(size_t)crow * 64 + dhalf * 32 + lq] = f2bf(o[dhalf][r]);
    }
}

extern "C" void kernel_launch(void* const* d_in, const int* in_sizes, int n_in,
                              void* d_out, int out_size, void* d_ws, size_t ws_size,
                              hipStream_t stream) {
  const float* x   = (const float*)d_in[0];
  const float* emb = (const float*)d_in[1];
  const float* Wq  = (const float*)d_in[2];
  const float* Wk  = (const float*)d_in[3];
  const float* Wv  = (const float*)d_in[4];
  const float* g1  = (const float*)d_in[5];
  const float* b1  = (const float*)d_in[6];
  const float* g2  = (const float*)d_in[7];
  const float* b2  = (const float*)d_in[8];
  const float* g3  = (const float*)d_in[9];
  const float* b3  = (const float*)d_in[10];
  const float* Wf1 = (const float*)d_in[11];
  const float* bf1 = (const float*)d_in[12];
  const float* Wf2 = (const float*)d_in[13];
  const float* bf2 = (const float*)d_in[14];
  float* out = (float*)d_out;

  char* ws = (char*)d_ws;
  size_t off = 0;
  auto alloc = [&](size_t bytes) { void* p = ws + off; off += (bytes + 255) & ~255ull; return p; };
  float* xt = (float*)alloc((size_t)NTOK * DMODEL * 4);
  u16* qkin = (u16*)alloc((size_t)NTOK * DCAT * 2);
  u16* hb   = (u16*)alloc((size_t)NTOK * DMODEL * 2);
  u16* r1   = (u16*)alloc((size_t)NTOK * DMODEL * 2);
  u16* qkvh = (u16*)alloc((size_t)3 * NTOK * DMODEL * 2);  // qhd | khd | vT contiguous
  u16* Tqkv = (u16*)alloc((size_t)1536 * DCAT * 2);
  u16* Tf1  = (u16*)alloc((size_t)DMODEL * DMODEL * 2);
  u16* Tf2  = (u16*)alloc((size_t)DMODEL * DMODEL * 2);
  u16* obuf = (u16*)alloc((size_t)4 * NHEAD * NTOK * DHEAD * 2);  // 16 MB
  float* lbuf = (float*)alloc((size_t)4 * NHEAD * NTOK * 4);      // 512 KB
  u16* qhd = qkvh;
  u16* khd = qkvh + (size_t)NTOK * DMODEL;
  u16* vTd = qkvh + (size_t)2 * NTOK * DMODEL;

  prep_kernel<<<2408, 256, 0, stream>>>(x, emb, Wq, Wk, Wv, Wf1, Wf2,
                                        g1, b1, g2, b2, xt, qkin, Tqkv, Tf1, Tf2);
  gemm_qkv_kernel<<<dim3(24, 32), 256, 0, stream>>>(qkin, Tqkv, qkvh);
  attn_kernel<<<512, 512, 0, stream>>>(qhd, khd, vTd, obuf, lbuf);
  ln3_kernel<<<1024, 256, 0, stream>>>(xt, g3, b3, hb, obuf, lbuf);
  gemm_kernel<3><<<dim3(8, 64), 256, 0, stream>>>(hb, DMODEL, Tf1, DMODEL, r1, nullptr, bf1, nullptr);
  gemm_kernel<4><<<dim3(8, 64), 256, 0, stream>>>(r1, DMODEL, Tf2, DMODEL, nullptr, out, bf2, xt);
}